// Round 8
// baseline (3937.434 us; speedup 1.0000x reference)
//
#include <hip/hip_runtime.h>
#include <hip/hip_bf16.h>

#define N_NODES 10000
#define N_EDGES 160000
#define TE 16   // edges per block (ONLY change vs round-5)

typedef __attribute__((ext_vector_type(8))) short bfrag_t;   // 8 x bf16
typedef __attribute__((ext_vector_type(4))) float facc_t;    // 4 x f32

__device__ inline short f2bf(float f) {
    union { float f; unsigned u; } x; x.f = f;
    unsigned r = x.u + 0x7FFFu + ((x.u >> 16) & 1u);
    return (short)(r >> 16);
}

// Pack W2 (256x1024 f32, row-major) into MFMA B fragments, bf16, with 1/16 scale folded.
// (known-good round-2/3/5 version)
__global__ void pack_w2(const float* __restrict__ w2, short* __restrict__ outp) {
    int g = blockIdx.x * blockDim.x + threadIdx.x;  // 0..262143
    int j    = g & 7;
    int lane = (g >> 3) & 63;
    int k    = (g >> 9) & 7;
    int nt   = (g >> 12) & 15;
    int p    = g >> 16;
    int row = k * 32 + ((lane >> 4) << 3) + j;
    int col = p * 256 + nt * 16 + (lane & 15);
    outp[g] = f2bf(w2[row * 1024 + col] * 0.0625f);
}

// ---- dst-sort infrastructure (unchanged, known-good) ----
__global__ void zero_counts(int* __restrict__ counts) {
    int i = blockIdx.x * blockDim.x + threadIdx.x;
    if (i < N_NODES) counts[i] = 0;
}

__global__ void hist_kernel(const int* __restrict__ edst, int* __restrict__ counts) {
    int e = blockIdx.x * blockDim.x + threadIdx.x;
    if (e < N_EDGES) atomicAdd(&counts[edst[e]], 1);
}

__global__ __launch_bounds__(256) void scan_kernel(const int* __restrict__ counts,
                                                   int* __restrict__ cursor) {
    __shared__ int part[256];
    const int t = threadIdx.x;
    const int CH = 40;
    int base = t * CH;
    int s = 0;
    for (int i = 0; i < CH; ++i) {
        int idx = base + i;
        if (idx < N_NODES) s += counts[idx];
    }
    part[t] = s;
    __syncthreads();
    for (int off = 1; off < 256; off <<= 1) {
        int add = (t >= off) ? part[t - off] : 0;
        __syncthreads();
        part[t] += add;
        __syncthreads();
    }
    int run = part[t] - s;
    for (int i = 0; i < CH; ++i) {
        int idx = base + i;
        if (idx < N_NODES) {
            cursor[idx] = run;
            run += counts[idx];
        }
    }
}

__global__ void scatter_kernel(const int* __restrict__ edst, int* __restrict__ cursor,
                               int* __restrict__ perm) {
    int e = blockIdx.x * blockDim.x + threadIdx.x;
    if (e < N_EDGES) {
        int pos = atomicAdd(&cursor[edst[e]], 1);
        perm[pos] = e;
    }
}

__global__ __launch_bounds__(256, 6) void conv_kernel(
    const int* __restrict__ perm,
    const int* __restrict__ esrc, const int* __restrict__ edst,
    const float* __restrict__ nodef, const float* __restrict__ esh,
    const float* __restrict__ ell, const float* __restrict__ w1,
    const short* __restrict__ w2p, const int* __restrict__ nn,
    float* __restrict__ outg)
{
    // hbuf: h (bf16, 16 rows x 512B, XOR-swizzled) during phases B/C;
    // r0..r3 (f32) after the post-C barrier. 6400B used of 8192.
    __shared__ __align__(16) char hbuf[TE * 512];               // 8 KB
    short* h_lds  = (short*)hbuf;
    float* r0_lds = (float*)hbuf;                               // [16][17] flat, 1088 B
    float* r1_lds = (float*)(hbuf + 1088);                      // [16][17]
    float* r2_lds = (float*)(hbuf + 2176);                      // [16][17]
    float* r3_lds = (float*)(hbuf + 3264);                      // [16][49], ends 6400
    // x_lds during phases B/C; vbuf (16x64 f32 = 4 KB) during phase D
    __shared__ __align__(16) float x_lds[TE][68];               // 4352 B
    float* vbuf = (float*)x_lds;
    __shared__ float a0_lds[TE][17];   // s0*y0
    __shared__ float a1_lds[TE][17];   // sum_i v1[u][i]*y1[i]
    __shared__ float sh_lds[TE][4];
    __shared__ float el_lds[TE][3];
    __shared__ int   src_lds[TE];
    __shared__ int   dst_lds[TE];
    __shared__ int   head_lds[TE];

    const int tid = threadIdx.x;
    const int e0  = blockIdx.x * TE;

    // ---- phase A: gathered edge-wise loads (via perm) ----
    if (tid < TE) {
        int pe = perm[e0 + tid];
        src_lds[tid] = esrc[pe];
        dst_lds[tid] = edst[pe];
        float4 s4 = *(const float4*)(esh + (size_t)pe * 4);
        sh_lds[tid][0] = s4.x; sh_lds[tid][1] = s4.y;
        sh_lds[tid][2] = s4.z; sh_lds[tid][3] = s4.w;
        const float* lp = ell + (size_t)pe * 3;
        el_lds[tid][0] = lp[0]; el_lds[tid][1] = lp[1]; el_lds[tid][2] = lp[2];
    }
    __syncthreads();

    // ---- phase B: x gather, h compute (to LDS bf16), coefficient precompute ----
    {
        int e = tid >> 4, part = tid & 15;         // 16 threads/edge, 4 floats each
        int s = src_lds[e];
        float4 f0 = *(const float4*)(nodef + (size_t)s * 64 + part * 4);
        *(float4*)(&x_lds[e][part * 4]) = f0;
    }
    {
        int e = tid >> 4, c0 = (tid & 15) * 16;    // 16 threads/edge, 16 cols each
        float l0 = el_lds[e][0], l1 = el_lds[e][1], l2 = el_lds[e][2];
        #pragma unroll
        for (int s8 = 0; s8 < 2; ++s8) {
            bfrag_t hv;
            #pragma unroll
            for (int m = 0; m < 8; ++m) {
                int c = c0 + s8 * 8 + m;
                float a = l0 * w1[c] + l1 * w1[256 + c] + l2 * w1[512 + c];
                a = fmaxf(a, 0.f) * 0.8164965809277260f;  // sqrt(2/3), relu scale folded
                hv[m] = f2bf(a);
            }
            int byte = (e * 512 + (c0 + s8 * 8) * 2) ^ ((e & 7) << 4);
            *(bfrag_t*)((char*)h_lds + byte) = hv;
        }
    }
    __syncthreads();
    {
        // one (e,u) per thread: TE*16 == 256
        int e = tid >> 4, u = tid & 15;
        float y0 = sh_lds[e][0];
        a0_lds[e][u] = x_lds[e][u] * y0;
        a1_lds[e][u] = x_lds[e][16 + u * 3 + 0] * sh_lds[e][1]
                     + x_lds[e][16 + u * 3 + 1] * sh_lds[e][2]
                     + x_lds[e][16 + u * 3 + 2] * sh_lds[e][3];
    }
    __syncthreads();

    // ---- phase C: MFMA GEMM (wave p == TP path p), 1 M-tile per wave ----
    const int lane = tid & 63;
    const int p    = tid >> 6;
    const int g    = lane >> 4;
    const int v    = lane & 15;

    float acc0[4];
    float acc3[4][3];
    #pragma unroll
    for (int r = 0; r < 4; ++r) {
        acc0[r] = 0.f;
        acc3[r][0] = 0.f; acc3[r][1] = 0.f; acc3[r][2] = 0.f;
    }

    const bfrag_t* Bp = (const bfrag_t*)w2p + (size_t)(p * 128) * 64 + lane;
    const int rb  = v * 512;
    const int swz = (v & 7) << 4;

    #pragma unroll
    for (int ntc = 0; ntc < 4; ++ntc) {
        facc_t acc[4];
        #pragma unroll
        for (int q = 0; q < 4; ++q)
            acc[q] = (facc_t){0.f, 0.f, 0.f, 0.f};

        #pragma unroll
        for (int k = 0; k < 8; ++k) {
            int koff = (k * 32 + 8 * g) * 2;
            bfrag_t a = *(const bfrag_t*)((const char*)h_lds + ((rb + koff) ^ swz));
            #pragma unroll
            for (int q = 0; q < 4; ++q) {
                bfrag_t b = Bp[(size_t)((ntc * 4 + q) * 8 + k) * 64];
                acc[q] = __builtin_amdgcn_mfma_f32_16x16x32_bf16(a, b, acc[q], 0, 0, 0);
            }
        }
        // TP reduction over u in this chunk (scalar reads, round-5 pattern)
        #pragma unroll
        for (int r = 0; r < 4; ++r) {
            int e = 4 * g + r;
            #pragma unroll
            for (int q = 0; q < 4; ++q) {
                int u = ntc * 4 + q;
                float wv = acc[q][r];
                if (p == 0)       acc0[r] += a0_lds[e][u] * wv;
                else if (p == 1)  acc0[r] += a1_lds[e][u] * wv;
                else if (p == 2)  acc0[r] += x_lds[e][u] * wv;
                else {
                    acc3[r][0] += x_lds[e][16 + u * 3 + 0] * wv;
                    acc3[r][1] += x_lds[e][16 + u * 3 + 1] * wv;
                    acc3[r][2] += x_lds[e][16 + u * 3 + 2] * wv;
                }
            }
        }
    }

    __syncthreads();   // ALL h_lds reads complete -> r* may overwrite hbuf

    #pragma unroll
    for (int r = 0; r < 4; ++r) {
        int e = 4 * g + r;
        if (p == 0)       r0_lds[e * 17 + v] = acc0[r];
        else if (p == 1)  r1_lds[e * 17 + v] = acc0[r];
        else if (p == 2)  r2_lds[e * 17 + v] = acc0[r];
        else {
            r3_lds[e * 49 + v * 3 + 0] = acc3[r][0];
            r3_lds[e * 49 + v * 3 + 1] = acc3[r][1];
            r3_lds[e * 49 + v * 3 + 2] = acc3[r][2];
        }
    }
    __syncthreads();   // r* ready; all x_lds/a*_lds reads done -> vbuf may alias x_lds

    // ---- phase D: combine per-edge outputs, run-merge by dst, reduced atomics ----
    {
        float scale = rsqrtf((float)nn[0]);
        const float pw0 = 0.17677669529663687f;          // sqrt(1/32); pw1/sqrt(3) == pw0
        float k0 = pw0 * scale;
        float k1 = k0 * 0.57735026918962576f;            // extra 1/sqrt(3) on path 1

        int e  = tid >> 4;
        int j0 = (tid & 15) * 4;
        float y0  = sh_lds[e][0];
        float y1x = sh_lds[e][1], y1y = sh_lds[e][2], y1z = sh_lds[e][3];
        #pragma unroll
        for (int jj = 0; jj < 4; ++jj) {
            int j = j0 + jj;
            float val;
            if (j < 16) {
                val = k0 * r0_lds[e * 17 + j] + k1 * r1_lds[e * 17 + j];
            } else {
                int t2 = j - 16;
                int vv = t2 / 3;
                int i  = t2 - vv * 3;
                float y1i = (i == 0) ? y1x : ((i == 1) ? y1y : y1z);
                val = k0 * (y1i * r2_lds[e * 17 + vv] + y0 * r3_lds[e * 49 + t2]);
            }
            vbuf[e * 64 + j] = val;
        }
    }
    if (tid < TE)
        head_lds[tid] = (tid == 0) || (dst_lds[tid] != dst_lds[tid - 1]);
    __syncthreads();
    {
        int e    = tid >> 4;
        int part = tid & 15;
        if (head_lds[e]) {
            int L = 1;
            while (e + L < TE && !head_lds[e + L]) ++L;
            float4 s0 = *(const float4*)(vbuf + e * 64 + part * 4);
            for (int i = 1; i < L; ++i) {
                float4 t0 = *(const float4*)(vbuf + (e + i) * 64 + part * 4);
                s0.x += t0.x; s0.y += t0.y; s0.z += t0.z; s0.w += t0.w;
            }
            float* op = outg + (size_t)dst_lds[e] * 64 + part * 4;
            atomicAdd(op + 0, s0.x); atomicAdd(op + 1, s0.y);
            atomicAdd(op + 2, s0.z); atomicAdd(op + 3, s0.w);
        }
    }
}

extern "C" void kernel_launch(void* const* d_in, const int* in_sizes, int n_in,
                              void* d_out, int out_size, void* d_ws, size_t ws_size,
                              hipStream_t stream) {
    const int*   esrc  = (const int*)d_in[0];
    const int*   edst  = (const int*)d_in[1];
    const float* nodef = (const float*)d_in[2];
    const float* esh   = (const float*)d_in[3];
    const float* ellv  = (const float*)d_in[4];
    const float* w1    = (const float*)d_in[5];
    const float* w2    = (const float*)d_in[6];
    const int*   nn    = (const int*)d_in[7];
    float* outg = (float*)d_out;

    char* ws = (char*)d_ws;
    short* w2p    = (short*)ws;                        // 512 KiB
    int*   counts = (int*)(ws + (512 << 10));          // 40 KB
    int*   cursor = (int*)(ws + (512 << 10) + 65536);  // 40 KB
    int*   permv  = (int*)(ws + (512 << 10) + 131072); // 640 KB

    hipMemsetAsync(d_out, 0, (size_t)out_size * sizeof(float), stream);
    pack_w2<<<1024, 256, 0, stream>>>(w2, w2p);
    zero_counts<<<(N_NODES + 255) / 256, 256, 0, stream>>>(counts);
    hist_kernel<<<N_EDGES / 256, 256, 0, stream>>>(edst, counts);
    scan_kernel<<<1, 256, 0, stream>>>(counts, cursor);
    scatter_kernel<<<N_EDGES / 256, 256, 0, stream>>>(edst, cursor, permv);
    conv_kernel<<<N_EDGES / TE, 256, 0, stream>>>(permv, esrc, edst, nodef, esh, ellv,
                                                  w1, w2p, nn, outg);
}

// Round 9
// 557.768 us; speedup vs baseline: 7.0593x; 7.0593x over previous
//
#include <hip/hip_runtime.h>
#include <hip/hip_bf16.h>

#define N_NODES 10000
#define N_EDGES 160000
#define TE 16   // edges per block

typedef __attribute__((ext_vector_type(8))) short bfrag_t;   // 8 x bf16
typedef __attribute__((ext_vector_type(4))) float facc_t;    // 4 x f32

__device__ inline short f2bf(float f) {
    union { float f; unsigned u; } x; x.f = f;
    unsigned r = x.u + 0x7FFFu + ((x.u >> 16) & 1u);
    return (short)(r >> 16);
}

// Pack W2 (256x1024 f32, row-major) into MFMA B fragments, bf16, with 1/16 scale folded.
// (known-good round-2/3/5 version)
__global__ void pack_w2(const float* __restrict__ w2, short* __restrict__ outp) {
    int g = blockIdx.x * blockDim.x + threadIdx.x;  // 0..262143
    int j    = g & 7;
    int lane = (g >> 3) & 63;
    int k    = (g >> 9) & 7;
    int nt   = (g >> 12) & 15;
    int p    = g >> 16;
    int row = k * 32 + ((lane >> 4) << 3) + j;
    int col = p * 256 + nt * 16 + (lane & 15);
    outp[g] = f2bf(w2[row * 1024 + col] * 0.0625f);
}

// ---- dst-sort infrastructure (unchanged, known-good) ----
__global__ void zero_counts(int* __restrict__ counts) {
    int i = blockIdx.x * blockDim.x + threadIdx.x;
    if (i < N_NODES) counts[i] = 0;
}

__global__ void hist_kernel(const int* __restrict__ edst, int* __restrict__ counts) {
    int e = blockIdx.x * blockDim.x + threadIdx.x;
    if (e < N_EDGES) atomicAdd(&counts[edst[e]], 1);
}

__global__ __launch_bounds__(256) void scan_kernel(const int* __restrict__ counts,
                                                   int* __restrict__ cursor) {
    __shared__ int part[256];
    const int t = threadIdx.x;
    const int CH = 40;
    int base = t * CH;
    int s = 0;
    for (int i = 0; i < CH; ++i) {
        int idx = base + i;
        if (idx < N_NODES) s += counts[idx];
    }
    part[t] = s;
    __syncthreads();
    for (int off = 1; off < 256; off <<= 1) {
        int add = (t >= off) ? part[t - off] : 0;
        __syncthreads();
        part[t] += add;
        __syncthreads();
    }
    int run = part[t] - s;
    for (int i = 0; i < CH; ++i) {
        int idx = base + i;
        if (idx < N_NODES) {
            cursor[idx] = run;
            run += counts[idx];
        }
    }
}

__global__ void scatter_kernel(const int* __restrict__ edst, int* __restrict__ cursor,
                               int* __restrict__ perm) {
    int e = blockIdx.x * blockDim.x + threadIdx.x;
    if (e < N_EDGES) {
        int pos = atomicAdd(&cursor[edst[e]], 1);
        perm[pos] = e;
    }
}

__global__ __launch_bounds__(256) void conv_kernel(
    const int* __restrict__ perm,
    const int* __restrict__ esrc, const int* __restrict__ edst,
    const float* __restrict__ nodef, const float* __restrict__ esh,
    const float* __restrict__ ell, const float* __restrict__ w1,
    const short* __restrict__ w2p, const int* __restrict__ nn,
    float* __restrict__ outg)
{
    // hbuf: h (bf16, 16 rows x 512B, XOR-swizzled) during phases B/C;
    // r0..r3 (f32) after the post-C barrier. 6400B used of 8192.
    __shared__ __align__(16) char hbuf[TE * 512];               // 8 KB
    short* h_lds  = (short*)hbuf;
    float* r0_lds = (float*)hbuf;                               // [16][17] flat, 1088 B
    float* r1_lds = (float*)(hbuf + 1088);                      // [16][17]
    float* r2_lds = (float*)(hbuf + 2176);                      // [16][17]
    float* r3_lds = (float*)(hbuf + 3264);                      // [16][49], ends 6400
    // x_lds during phases B/C; vbuf (16x64 f32 = 4 KB) during phase D
    __shared__ __align__(16) float x_lds[TE][68];               // 4352 B
    float* vbuf = (float*)x_lds;
    __shared__ float a0_lds[TE][17];   // s0*y0
    __shared__ float a1_lds[TE][17];   // sum_i v1[u][i]*y1[i]
    __shared__ float sh_lds[TE][4];
    __shared__ float el_lds[TE][3];
    __shared__ int   src_lds[TE];
    __shared__ int   dst_lds[TE];
    __shared__ int   head_lds[TE];

    const int tid = threadIdx.x;
    const int e0  = blockIdx.x * TE;

    // ---- phase A: gathered edge-wise loads (via perm) ----
    if (tid < TE) {
        int pe = perm[e0 + tid];
        src_lds[tid] = esrc[pe];
        dst_lds[tid] = edst[pe];
        float4 s4 = *(const float4*)(esh + (size_t)pe * 4);
        sh_lds[tid][0] = s4.x; sh_lds[tid][1] = s4.y;
        sh_lds[tid][2] = s4.z; sh_lds[tid][3] = s4.w;
        const float* lp = ell + (size_t)pe * 3;
        el_lds[tid][0] = lp[0]; el_lds[tid][1] = lp[1]; el_lds[tid][2] = lp[2];
    }
    __syncthreads();

    // ---- phase B: x gather, h compute (to LDS bf16), coefficient precompute ----
    {
        int e = tid >> 4, part = tid & 15;         // 16 threads/edge, 4 floats each
        int s = src_lds[e];
        float4 f0 = *(const float4*)(nodef + (size_t)s * 64 + part * 4);
        *(float4*)(&x_lds[e][part * 4]) = f0;
    }
    {
        int e = tid >> 4, c0 = (tid & 15) * 16;    // 16 threads/edge, 16 cols each
        float l0 = el_lds[e][0], l1 = el_lds[e][1], l2 = el_lds[e][2];
        #pragma unroll
        for (int s8 = 0; s8 < 2; ++s8) {
            bfrag_t hv;
            #pragma unroll
            for (int m = 0; m < 8; ++m) {
                int c = c0 + s8 * 8 + m;
                float a = l0 * w1[c] + l1 * w1[256 + c] + l2 * w1[512 + c];
                a = fmaxf(a, 0.f) * 0.8164965809277260f;  // sqrt(2/3), relu scale folded
                hv[m] = f2bf(a);
            }
            int byte = (e * 512 + (c0 + s8 * 8) * 2) ^ ((e & 7) << 4);
            *(bfrag_t*)((char*)h_lds + byte) = hv;
        }
    }
    __syncthreads();
    {
        // one (e,u) per thread: TE*16 == 256
        int e = tid >> 4, u = tid & 15;
        float y0 = sh_lds[e][0];
        a0_lds[e][u] = x_lds[e][u] * y0;
        a1_lds[e][u] = x_lds[e][16 + u * 3 + 0] * sh_lds[e][1]
                     + x_lds[e][16 + u * 3 + 1] * sh_lds[e][2]
                     + x_lds[e][16 + u * 3 + 2] * sh_lds[e][3];
    }
    __syncthreads();

    // ---- phase C: MFMA GEMM (wave p == TP path p), 1 M-tile per wave ----
    const int lane = tid & 63;
    const int p    = tid >> 6;
    const int g    = lane >> 4;
    const int v    = lane & 15;

    float acc0[4];
    float acc3[4][3];
    #pragma unroll
    for (int r = 0; r < 4; ++r) {
        acc0[r] = 0.f;
        acc3[r][0] = 0.f; acc3[r][1] = 0.f; acc3[r][2] = 0.f;
    }

    const bfrag_t* Bp = (const bfrag_t*)w2p + (size_t)(p * 128) * 64 + lane;
    const int rb  = v * 512;
    const int swz = (v & 7) << 4;

    #pragma unroll
    for (int ntc = 0; ntc < 4; ++ntc) {
        facc_t acc[4];
        #pragma unroll
        for (int q = 0; q < 4; ++q)
            acc[q] = (facc_t){0.f, 0.f, 0.f, 0.f};

        #pragma unroll
        for (int k = 0; k < 8; ++k) {
            int koff = (k * 32 + 8 * g) * 2;
            bfrag_t a = *(const bfrag_t*)((const char*)h_lds + ((rb + koff) ^ swz));
            #pragma unroll
            for (int q = 0; q < 4; ++q) {
                bfrag_t b = Bp[(size_t)((ntc * 4 + q) * 8 + k) * 64];
                acc[q] = __builtin_amdgcn_mfma_f32_16x16x32_bf16(a, b, acc[q], 0, 0, 0);
            }
        }
        // TP reduction over u in this chunk (scalar reads, round-5 pattern)
        #pragma unroll
        for (int r = 0; r < 4; ++r) {
            int e = 4 * g + r;
            #pragma unroll
            for (int q = 0; q < 4; ++q) {
                int u = ntc * 4 + q;
                float wv = acc[q][r];
                if (p == 0)       acc0[r] += a0_lds[e][u] * wv;
                else if (p == 1)  acc0[r] += a1_lds[e][u] * wv;
                else if (p == 2)  acc0[r] += x_lds[e][u] * wv;
                else {
                    acc3[r][0] += x_lds[e][16 + u * 3 + 0] * wv;
                    acc3[r][1] += x_lds[e][16 + u * 3 + 1] * wv;
                    acc3[r][2] += x_lds[e][16 + u * 3 + 2] * wv;
                }
            }
        }
    }

    __syncthreads();   // ALL h_lds reads complete -> r* may overwrite hbuf

    #pragma unroll
    for (int r = 0; r < 4; ++r) {
        int e = 4 * g + r;
        if (p == 0)       r0_lds[e * 17 + v] = acc0[r];
        else if (p == 1)  r1_lds[e * 17 + v] = acc0[r];
        else if (p == 2)  r2_lds[e * 17 + v] = acc0[r];
        else {
            r3_lds[e * 49 + v * 3 + 0] = acc3[r][0];
            r3_lds[e * 49 + v * 3 + 1] = acc3[r][1];
            r3_lds[e * 49 + v * 3 + 2] = acc3[r][2];
        }
    }
    __syncthreads();   // r* ready; all x_lds/a*_lds reads done -> vbuf may alias x_lds

    // ---- phase D: combine per-edge outputs, run-merge by dst, reduced atomics ----
    {
        float scale = rsqrtf((float)nn[0]);
        const float pw0 = 0.17677669529663687f;          // sqrt(1/32); pw1/sqrt(3) == pw0
        float k0 = pw0 * scale;
        float k1 = k0 * 0.57735026918962576f;            // extra 1/sqrt(3) on path 1

        int e  = tid >> 4;
        int j0 = (tid & 15) * 4;
        float y0  = sh_lds[e][0];
        float y1x = sh_lds[e][1], y1y = sh_lds[e][2], y1z = sh_lds[e][3];
        #pragma unroll
        for (int jj = 0; jj < 4; ++jj) {
            int j = j0 + jj;
            float val;
            if (j < 16) {
                val = k0 * r0_lds[e * 17 + j] + k1 * r1_lds[e * 17 + j];
            } else {
                int t2 = j - 16;
                int vv = t2 / 3;
                int i  = t2 - vv * 3;
                float y1i = (i == 0) ? y1x : ((i == 1) ? y1y : y1z);
                val = k0 * (y1i * r2_lds[e * 17 + vv] + y0 * r3_lds[e * 49 + t2]);
            }
            vbuf[e * 64 + j] = val;
        }
    }
    if (tid < TE)
        head_lds[tid] = (tid == 0) || (dst_lds[tid] != dst_lds[tid - 1]);
    __syncthreads();
    {
        int e    = tid >> 4;
        int part = tid & 15;
        if (head_lds[e]) {
            int L = 1;
            while (e + L < TE && !head_lds[e + L]) ++L;
            float4 s0 = *(const float4*)(vbuf + e * 64 + part * 4);
            for (int i = 1; i < L; ++i) {
                float4 t0 = *(const float4*)(vbuf + (e + i) * 64 + part * 4);
                s0.x += t0.x; s0.y += t0.y; s0.z += t0.z; s0.w += t0.w;
            }
            float* op = outg + (size_t)dst_lds[e] * 64 + part * 4;
            atomicAdd(op + 0, s0.x); atomicAdd(op + 1, s0.y);
            atomicAdd(op + 2, s0.z); atomicAdd(op + 3, s0.w);
        }
    }
}

extern "C" void kernel_launch(void* const* d_in, const int* in_sizes, int n_in,
                              void* d_out, int out_size, void* d_ws, size_t ws_size,
                              hipStream_t stream) {
    const int*   esrc  = (const int*)d_in[0];
    const int*   edst  = (const int*)d_in[1];
    const float* nodef = (const float*)d_in[2];
    const float* esh   = (const float*)d_in[3];
    const float* ellv  = (const float*)d_in[4];
    const float* w1    = (const float*)d_in[5];
    const float* w2    = (const float*)d_in[6];
    const int*   nn    = (const int*)d_in[7];
    float* outg = (float*)d_out;

    char* ws = (char*)d_ws;
    short* w2p    = (short*)ws;                        // 512 KiB
    int*   counts = (int*)(ws + (512 << 10));          // 40 KB
    int*   cursor = (int*)(ws + (512 << 10) + 65536);  // 40 KB
    int*   permv  = (int*)(ws + (512 << 10) + 131072); // 640 KB

    hipMemsetAsync(d_out, 0, (size_t)out_size * sizeof(float), stream);
    pack_w2<<<1024, 256, 0, stream>>>(w2, w2p);
    zero_counts<<<(N_NODES + 255) / 256, 256, 0, stream>>>(counts);
    hist_kernel<<<N_EDGES / 256, 256, 0, stream>>>(edst, counts);
    scan_kernel<<<1, 256, 0, stream>>>(counts, cursor);
    scatter_kernel<<<N_EDGES / 256, 256, 0, stream>>>(edst, cursor, permv);
    conv_kernel<<<N_EDGES / TE, 256, 0, stream>>>(permv, esrc, edst, nodef, esh, ellv,
                                                  w1, w2p, nn, outg);
}

// Round 10
// 415.289 us; speedup vs baseline: 9.4812x; 1.3431x over previous
//
#include <hip/hip_runtime.h>
#include <hip/hip_bf16.h>

#define N_NODES 10000
#define N_EDGES 160000
#define TE 32   // edges per block (r5 proven base)

typedef __attribute__((ext_vector_type(8))) short bfrag_t;   // 8 x bf16
typedef __attribute__((ext_vector_type(4))) float facc_t;    // 4 x f32

__device__ inline short f2bf(float f) {
    union { float f; unsigned u; } x; x.f = f;
    unsigned r = x.u + 0x7FFFu + ((x.u >> 16) & 1u);
    return (short)(r >> 16);
}

// Pack W2 (256x1024 f32, row-major) into MFMA B fragments, bf16, with 1/16 scale folded.
// (known-good round-2/3/5 version)
__global__ void pack_w2(const float* __restrict__ w2, short* __restrict__ outp) {
    int g = blockIdx.x * blockDim.x + threadIdx.x;  // 0..262143
    int j    = g & 7;
    int lane = (g >> 3) & 63;
    int k    = (g >> 9) & 7;
    int nt   = (g >> 12) & 15;
    int p    = g >> 16;
    int row = k * 32 + ((lane >> 4) << 3) + j;
    int col = p * 256 + nt * 16 + (lane & 15);
    outp[g] = f2bf(w2[row * 1024 + col] * 0.0625f);
}

// ---- dst-sort infrastructure (unchanged, known-good) ----
__global__ void zero_counts(int* __restrict__ counts) {
    int i = blockIdx.x * blockDim.x + threadIdx.x;
    if (i < N_NODES) counts[i] = 0;
}

__global__ void hist_kernel(const int* __restrict__ edst, int* __restrict__ counts) {
    int e = blockIdx.x * blockDim.x + threadIdx.x;
    if (e < N_EDGES) atomicAdd(&counts[edst[e]], 1);
}

__global__ __launch_bounds__(256) void scan_kernel(const int* __restrict__ counts,
                                                   int* __restrict__ cursor) {
    __shared__ int part[256];
    const int t = threadIdx.x;
    const int CH = 40;
    int base = t * CH;
    int s = 0;
    for (int i = 0; i < CH; ++i) {
        int idx = base + i;
        if (idx < N_NODES) s += counts[idx];
    }
    part[t] = s;
    __syncthreads();
    for (int off = 1; off < 256; off <<= 1) {
        int add = (t >= off) ? part[t - off] : 0;
        __syncthreads();
        part[t] += add;
        __syncthreads();
    }
    int run = part[t] - s;
    for (int i = 0; i < CH; ++i) {
        int idx = base + i;
        if (idx < N_NODES) {
            cursor[idx] = run;
            run += counts[idx];
        }
    }
}

__global__ void scatter_kernel(const int* __restrict__ edst, int* __restrict__ cursor,
                               int* __restrict__ perm) {
    int e = blockIdx.x * blockDim.x + threadIdx.x;
    if (e < N_EDGES) {
        int pos = atomicAdd(&cursor[edst[e]], 1);
        perm[pos] = e;
    }
}

__global__ __launch_bounds__(256) void conv_kernel(
    const int* __restrict__ perm,
    const int* __restrict__ esrc, const int* __restrict__ edst,
    const float* __restrict__ nodef, const float* __restrict__ esh,
    const float* __restrict__ ell, const float* __restrict__ w1,
    const short* __restrict__ w2p, const int* __restrict__ nn,
    float* __restrict__ outg)
{
    // hbuf: h (bf16, swizzled) during phases B/C; r0..r3 (f32) after the post-C barrier
    __shared__ __align__(16) char hbuf[TE * 512];               // 16 KB
    short* h_lds  = (short*)hbuf;
    float* r0_lds = (float*)hbuf;                               // [TE][17] flat, 2176 B
    float* r1_lds = (float*)(hbuf + 2176);                      // [TE][17]
    float* r2_lds = (float*)(hbuf + 4352);                      // [TE][17]
    float* r3_lds = (float*)(hbuf + 6528);                      // [TE][49], ends 12800
    // x_lds during phases B/C; vbuf (32x68 f32, stride 68 = conflict-free) in phase D
    __shared__ __align__(16) float x_lds[TE][68];               // 8704 B
    float* vbuf = (float*)x_lds;
    __shared__ float a0_lds[TE][17];   // s0*y0
    __shared__ float a1_lds[TE][17];   // sum_i v1[u][i]*y1[i]
    __shared__ float sh_lds[TE][4];
    __shared__ float el_lds[TE][3];
    __shared__ int   src_lds[TE];
    __shared__ int   dst_lds[TE];
    __shared__ int   head_lds[TE];

    const int tid = threadIdx.x;
    const int e0  = blockIdx.x * TE;

    // ---- phase A: gathered edge-wise loads (via perm) ----
    if (tid < TE) {
        int pe = perm[e0 + tid];
        src_lds[tid] = esrc[pe];
        dst_lds[tid] = edst[pe];
        float4 s4 = *(const float4*)(esh + (size_t)pe * 4);
        sh_lds[tid][0] = s4.x; sh_lds[tid][1] = s4.y;
        sh_lds[tid][2] = s4.z; sh_lds[tid][3] = s4.w;
        const float* lp = ell + (size_t)pe * 3;
        el_lds[tid][0] = lp[0]; el_lds[tid][1] = lp[1]; el_lds[tid][2] = lp[2];
    }
    __syncthreads();

    // ---- phase B: x gather, h compute (to LDS bf16), coefficient precompute ----
    {
        int e = tid >> 3, part = tid & 7;
        int s = src_lds[e];
        const float4* sp = (const float4*)(nodef + (size_t)s * 64 + part * 8);
        float4 u0 = sp[0], u1 = sp[1];
        float* xr = &x_lds[e][part * 8];
        *(float4*)(xr)     = u0;
        *(float4*)(xr + 4) = u1;
    }
    {
        int e = tid >> 3, c0 = (tid & 7) * 32;
        float l0 = el_lds[e][0], l1 = el_lds[e][1], l2 = el_lds[e][2];
        #pragma unroll
        for (int s = 0; s < 4; ++s) {
            bfrag_t hv;
            #pragma unroll
            for (int m = 0; m < 8; ++m) {
                int c = c0 + s * 8 + m;
                float a = l0 * w1[c] + l1 * w1[256 + c] + l2 * w1[512 + c];
                a = fmaxf(a, 0.f) * 0.8164965809277260f;  // sqrt(2/3), relu scale folded
                hv[m] = f2bf(a);
            }
            int byte = (e * 512 + (c0 + s * 8) * 2) ^ ((e & 7) << 4);
            *(bfrag_t*)((char*)h_lds + byte) = hv;
        }
    }
    __syncthreads();
    {
        #pragma unroll
        for (int q = tid; q < TE * 16; q += 256) {
            int e = q >> 4, u = q & 15;
            float y0 = sh_lds[e][0];
            a0_lds[e][u] = x_lds[e][u] * y0;
            a1_lds[e][u] = x_lds[e][16 + u * 3 + 0] * sh_lds[e][1]
                         + x_lds[e][16 + u * 3 + 1] * sh_lds[e][2]
                         + x_lds[e][16 + u * 3 + 2] * sh_lds[e][3];
        }
    }
    __syncthreads();

    // ---- phase C: MFMA GEMM (wave p == TP path p) fused with TP reduction ----
    // B-fragment k-quad double-buffer: prefetch (k+1)'s 4 frags while MFMAing k.
    const int lane = tid & 63;
    const int p    = tid >> 6;
    const int g    = lane >> 4;
    const int v    = lane & 15;

    float acc0[2][4];
    float acc3[2][4][3];
    #pragma unroll
    for (int mt = 0; mt < 2; ++mt)
        #pragma unroll
        for (int r = 0; r < 4; ++r) {
            acc0[mt][r] = 0.f;
            acc3[mt][r][0] = 0.f; acc3[mt][r][1] = 0.f; acc3[mt][r][2] = 0.f;
        }

    const bfrag_t* Bp = (const bfrag_t*)w2p + (size_t)(p * 128) * 64 + lane;

    const int rb0 = v * 512;
    const int rb1 = (16 + v) * 512;
    const int swz = (v & 7) << 4;

    // prologue: load ntc=0, k=0 quad
    bfrag_t bq[4], bqn[4];
    #pragma unroll
    for (int q = 0; q < 4; ++q)
        bq[q] = Bp[(size_t)((q) * 8 + 0) * 64];

    #pragma unroll
    for (int ntc = 0; ntc < 4; ++ntc) {
        facc_t acc[2][4];
        #pragma unroll
        for (int mt = 0; mt < 2; ++mt)
            #pragma unroll
            for (int q = 0; q < 4; ++q)
                acc[mt][q] = (facc_t){0.f, 0.f, 0.f, 0.f};

        #pragma unroll
        for (int k = 0; k < 8; ++k) {
            // prefetch next k-quad (or next ntc's k=0 quad)
            if (!(ntc == 3 && k == 7)) {
                int nntc = (k == 7) ? ntc + 1 : ntc;
                int nk   = (k == 7) ? 0 : k + 1;
                #pragma unroll
                for (int q = 0; q < 4; ++q)
                    bqn[q] = Bp[(size_t)((nntc * 4 + q) * 8 + nk) * 64];
            }
            int koff = (k * 32 + 8 * g) * 2;
            bfrag_t a0 = *(const bfrag_t*)((const char*)h_lds + ((rb0 + koff) ^ swz));
            bfrag_t a1 = *(const bfrag_t*)((const char*)h_lds + ((rb1 + koff) ^ swz));
            #pragma unroll
            for (int q = 0; q < 4; ++q) {
                acc[0][q] = __builtin_amdgcn_mfma_f32_16x16x32_bf16(a0, bq[q], acc[0][q], 0, 0, 0);
                acc[1][q] = __builtin_amdgcn_mfma_f32_16x16x32_bf16(a1, bq[q], acc[1][q], 0, 0, 0);
            }
            #pragma unroll
            for (int q = 0; q < 4; ++q)
                bq[q] = bqn[q];
        }
        // partial TP reduction over u = nt for this chunk (unchanged)
        #pragma unroll
        for (int mt = 0; mt < 2; ++mt)
            #pragma unroll
            for (int r = 0; r < 4; ++r) {
                int e = mt * 16 + 4 * g + r;
                #pragma unroll
                for (int q = 0; q < 4; ++q) {
                    int u = ntc * 4 + q;
                    float wv = acc[mt][q][r];
                    if (p == 0)       acc0[mt][r] += a0_lds[e][u] * wv;
                    else if (p == 1)  acc0[mt][r] += a1_lds[e][u] * wv;
                    else if (p == 2)  acc0[mt][r] += x_lds[e][u] * wv;
                    else {
                        acc3[mt][r][0] += x_lds[e][16 + u * 3 + 0] * wv;
                        acc3[mt][r][1] += x_lds[e][16 + u * 3 + 1] * wv;
                        acc3[mt][r][2] += x_lds[e][16 + u * 3 + 2] * wv;
                    }
                }
            }
    }

    __syncthreads();   // ALL h_lds reads complete -> r* may overwrite hbuf

    #pragma unroll
    for (int mt = 0; mt < 2; ++mt)
        #pragma unroll
        for (int r = 0; r < 4; ++r) {
            int e = mt * 16 + 4 * g + r;
            if (p == 0)       r0_lds[e * 17 + v] = acc0[mt][r];
            else if (p == 1)  r1_lds[e * 17 + v] = acc0[mt][r];
            else if (p == 2)  r2_lds[e * 17 + v] = acc0[mt][r];
            else {
                r3_lds[e * 49 + v * 3 + 0] = acc3[mt][r][0];
                r3_lds[e * 49 + v * 3 + 1] = acc3[mt][r][1];
                r3_lds[e * 49 + v * 3 + 2] = acc3[mt][r][2];
            }
        }
    __syncthreads();   // r* ready; all x_lds/a*_lds reads done -> vbuf may alias x_lds

    // ---- phase D: combine per-edge outputs, run-merge by dst, reduced atomics ----
    // vbuf stride 68 (not 64): bank = (4e+j)&31 -> 2-way max (free), was 8-way at stride 64
    {
        float scale = rsqrtf((float)nn[0]);
        const float pw0 = 0.17677669529663687f;          // sqrt(1/32); pw1/sqrt(3) == pw0
        float k0 = pw0 * scale;
        float k1 = k0 * 0.57735026918962576f;            // extra 1/sqrt(3) on path 1

        int e  = tid >> 3;
        int j0 = (tid & 7) * 8;
        float y0  = sh_lds[e][0];
        float y1x = sh_lds[e][1], y1y = sh_lds[e][2], y1z = sh_lds[e][3];
        #pragma unroll
        for (int jj = 0; jj < 8; ++jj) {
            int j = j0 + jj;
            float val;
            if (j < 16) {
                val = k0 * r0_lds[e * 17 + j] + k1 * r1_lds[e * 17 + j];
            } else {
                int t2 = j - 16;
                int vv = t2 / 3;
                int i  = t2 - vv * 3;
                float y1i = (i == 0) ? y1x : ((i == 1) ? y1y : y1z);
                val = k0 * (y1i * r2_lds[e * 17 + vv] + y0 * r3_lds[e * 49 + t2]);
            }
            vbuf[e * 68 + j] = val;
        }
    }
    if (tid < TE)
        head_lds[tid] = (tid == 0) || (dst_lds[tid] != dst_lds[tid - 1]);
    __syncthreads();
    {
        int e   = tid >> 3;
        int oct = tid & 7;
        if (head_lds[e]) {
            int L = 1;
            while (e + L < TE && !head_lds[e + L]) ++L;
            float4 s0 = *(const float4*)(vbuf + e * 68 + oct * 8);
            float4 s1 = *(const float4*)(vbuf + e * 68 + oct * 8 + 4);
            for (int i = 1; i < L; ++i) {
                const float4* q = (const float4*)(vbuf + (e + i) * 68 + oct * 8);
                float4 t0 = q[0], t1 = q[1];
                s0.x += t0.x; s0.y += t0.y; s0.z += t0.z; s0.w += t0.w;
                s1.x += t1.x; s1.y += t1.y; s1.z += t1.z; s1.w += t1.w;
            }
            float* op = outg + (size_t)dst_lds[e] * 64 + oct * 8;
            atomicAdd(op + 0, s0.x); atomicAdd(op + 1, s0.y);
            atomicAdd(op + 2, s0.z); atomicAdd(op + 3, s0.w);
            atomicAdd(op + 4, s1.x); atomicAdd(op + 5, s1.y);
            atomicAdd(op + 6, s1.z); atomicAdd(op + 7, s1.w);
        }
    }
}

extern "C" void kernel_launch(void* const* d_in, const int* in_sizes, int n_in,
                              void* d_out, int out_size, void* d_ws, size_t ws_size,
                              hipStream_t stream) {
    const int*   esrc  = (const int*)d_in[0];
    const int*   edst  = (const int*)d_in[1];
    const float* nodef = (const float*)d_in[2];
    const float* esh   = (const float*)d_in[3];
    const float* ellv  = (const float*)d_in[4];
    const float* w1    = (const float*)d_in[5];
    const float* w2    = (const float*)d_in[6];
    const int*   nn    = (const int*)d_in[7];
    float* outg = (float*)d_out;

    char* ws = (char*)d_ws;
    short* w2p    = (short*)ws;                        // 512 KiB
    int*   counts = (int*)(ws + (512 << 10));          // 40 KB
    int*   cursor = (int*)(ws + (512 << 10) + 65536);  // 40 KB
    int*   permv  = (int*)(ws + (512 << 10) + 131072); // 640 KB

    hipMemsetAsync(d_out, 0, (size_t)out_size * sizeof(float), stream);
    pack_w2<<<1024, 256, 0, stream>>>(w2, w2p);
    zero_counts<<<(N_NODES + 255) / 256, 256, 0, stream>>>(counts);
    hist_kernel<<<N_EDGES / 256, 256, 0, stream>>>(edst, counts);
    scan_kernel<<<1, 256, 0, stream>>>(counts, cursor);
    scatter_kernel<<<N_EDGES / 256, 256, 0, stream>>>(edst, cursor, permv);
    conv_kernel<<<N_EDGES / TE, 256, 0, stream>>>(permv, esrc, edst, nodef, esh, ellv,
                                                  w1, w2p, nn, outg);
}

// Round 11
// 412.786 us; speedup vs baseline: 9.5387x; 1.0061x over previous
//
#include <hip/hip_runtime.h>
#include <hip/hip_bf16.h>

#define N_NODES 10000
#define N_EDGES 160000
#define TE 64   // edges per block; 512-thread blocks, 8 waves

typedef __attribute__((ext_vector_type(8))) short bfrag_t;   // 8 x bf16
typedef __attribute__((ext_vector_type(4))) float facc_t;    // 4 x f32

__device__ inline short f2bf(float f) {
    union { float f; unsigned u; } x; x.f = f;
    unsigned r = x.u + 0x7FFFu + ((x.u >> 16) & 1u);
    return (short)(r >> 16);
}

// Pack W2 (256x1024 f32, row-major) into MFMA B fragments, bf16, 1/16 folded.
// (known-good round-2/3/5 version)
__global__ void pack_w2(const float* __restrict__ w2, short* __restrict__ outp) {
    int g = blockIdx.x * blockDim.x + threadIdx.x;  // 0..262143
    int j    = g & 7;
    int lane = (g >> 3) & 63;
    int k    = (g >> 9) & 7;
    int nt   = (g >> 12) & 15;
    int p    = g >> 16;
    int row = k * 32 + ((lane >> 4) << 3) + j;
    int col = p * 256 + nt * 16 + (lane & 15);
    outp[g] = f2bf(w2[row * 1024 + col] * 0.0625f);
}

// ---- dst-sort infrastructure (unchanged, known-good) ----
__global__ void zero_counts(int* __restrict__ counts) {
    int i = blockIdx.x * blockDim.x + threadIdx.x;
    if (i < N_NODES) counts[i] = 0;
}

__global__ void hist_kernel(const int* __restrict__ edst, int* __restrict__ counts) {
    int e = blockIdx.x * blockDim.x + threadIdx.x;
    if (e < N_EDGES) atomicAdd(&counts[edst[e]], 1);
}

__global__ __launch_bounds__(256) void scan_kernel(const int* __restrict__ counts,
                                                   int* __restrict__ cursor) {
    __shared__ int part[256];
    const int t = threadIdx.x;
    const int CH = 40;
    int base = t * CH;
    int s = 0;
    for (int i = 0; i < CH; ++i) {
        int idx = base + i;
        if (idx < N_NODES) s += counts[idx];
    }
    part[t] = s;
    __syncthreads();
    for (int off = 1; off < 256; off <<= 1) {
        int add = (t >= off) ? part[t - off] : 0;
        __syncthreads();
        part[t] += add;
        __syncthreads();
    }
    int run = part[t] - s;
    for (int i = 0; i < CH; ++i) {
        int idx = base + i;
        if (idx < N_NODES) {
            cursor[idx] = run;
            run += counts[idx];
        }
    }
}

__global__ void scatter_kernel(const int* __restrict__ edst, int* __restrict__ cursor,
                               int* __restrict__ perm) {
    int e = blockIdx.x * blockDim.x + threadIdx.x;
    if (e < N_EDGES) {
        int pos = atomicAdd(&cursor[edst[e]], 1);
        perm[pos] = e;
    }
}

__global__ __launch_bounds__(512) void conv_kernel(
    const int* __restrict__ perm,
    const int* __restrict__ esrc, const int* __restrict__ edst,
    const float* __restrict__ nodef, const float* __restrict__ esh,
    const float* __restrict__ ell, const float* __restrict__ w1,
    const short* __restrict__ w2p, const int* __restrict__ nn,
    float* __restrict__ outg)
{
    // hbuf: h (bf16, 64 rows x 512B, XOR-swizzled) during phases B/C;
    // r0..r3 (f32) after the post-C barrier (25600B of 32768).
    __shared__ __align__(16) char hbuf[TE * 512];               // 32 KB
    short* h_lds  = (short*)hbuf;
    float* r0_lds = (float*)hbuf;                               // [64][17], 4352 B
    float* r1_lds = (float*)(hbuf + 4352);                      // [64][17]
    float* r2_lds = (float*)(hbuf + 8704);                      // [64][17]
    float* r3_lds = (float*)(hbuf + 13056);                     // [64][49], ends 25600
    // x_lds during phases B/C; vbuf (64x68 f32, stride 68) during phase D
    __shared__ __align__(16) float x_lds[TE][68];               // 17408 B
    float* vbuf = (float*)x_lds;
    __shared__ float a0_lds[TE][17];   // s0*y0
    __shared__ float a1_lds[TE][17];   // sum_i v1[u][i]*y1[i]
    __shared__ float sh_lds[TE][4];
    __shared__ float el_lds[TE][3];
    __shared__ int   src_lds[TE];
    __shared__ int   dst_lds[TE];
    __shared__ int   head_lds[TE];

    const int tid = threadIdx.x;
    const int e0  = blockIdx.x * TE;

    // ---- phase A: gathered edge-wise loads (via perm) ----
    if (tid < TE) {
        int pe = perm[e0 + tid];
        src_lds[tid] = esrc[pe];
        dst_lds[tid] = edst[pe];
        float4 s4 = *(const float4*)(esh + (size_t)pe * 4);
        sh_lds[tid][0] = s4.x; sh_lds[tid][1] = s4.y;
        sh_lds[tid][2] = s4.z; sh_lds[tid][3] = s4.w;
        const float* lp = ell + (size_t)pe * 3;
        el_lds[tid][0] = lp[0]; el_lds[tid][1] = lp[1]; el_lds[tid][2] = lp[2];
    }
    __syncthreads();

    // ---- phase B: x gather + h compute (r5 per-thread shapes, 8 thr/edge) ----
    {
        int e = tid >> 3, part = tid & 7;
        int s = src_lds[e];
        const float4* sp = (const float4*)(nodef + (size_t)s * 64 + part * 8);
        float4 u0 = sp[0], u1 = sp[1];
        float* xr = &x_lds[e][part * 8];
        *(float4*)(xr)     = u0;
        *(float4*)(xr + 4) = u1;
    }
    {
        int e = tid >> 3, c0 = (tid & 7) * 32;
        float l0 = el_lds[e][0], l1 = el_lds[e][1], l2 = el_lds[e][2];
        #pragma unroll
        for (int s = 0; s < 4; ++s) {
            bfrag_t hv;
            #pragma unroll
            for (int m = 0; m < 8; ++m) {
                int c = c0 + s * 8 + m;
                float a = l0 * w1[c] + l1 * w1[256 + c] + l2 * w1[512 + c];
                a = fmaxf(a, 0.f) * 0.8164965809277260f;  // sqrt(2/3), relu scale folded
                hv[m] = f2bf(a);
            }
            int byte = (e * 512 + (c0 + s * 8) * 2) ^ ((e & 7) << 4);
            *(bfrag_t*)((char*)h_lds + byte) = hv;
        }
    }
    __syncthreads();
    {
        #pragma unroll
        for (int q = tid; q < TE * 16; q += 512) {
            int e = q >> 4, u = q & 15;
            float y0 = sh_lds[e][0];
            a0_lds[e][u] = x_lds[e][u] * y0;
            a1_lds[e][u] = x_lds[e][16 + u * 3 + 0] * sh_lds[e][1]
                         + x_lds[e][16 + u * 3 + 1] * sh_lds[e][2]
                         + x_lds[e][16 + u * 3 + 2] * sh_lds[e][3];
        }
    }
    __syncthreads();

    // ---- phase C: streaming MFMA. wave = (m-tile, path-pair); A-strip in regs ----
    const int lane = tid & 63;
    const int wv   = tid >> 6;        // 0..7
    const int mw   = wv & 3;          // m-tile: edges [16*mw, 16*mw+16)
    const int ph   = wv >> 1 >> 1;    // 0: paths {0,1}; 1: paths {2,3}
    const int g    = lane >> 4;
    const int v    = lane & 15;

    const int row  = 16 * mw + v;
    const int rbase = row * 512;
    const int swz   = (v & 7) << 4;   // (row&7)==(v&7) since 16*mw keeps low bits

    // A k-strip for this wave's m-tile: 8 frags, loaded once (32 VGPR)
    bfrag_t astrip[8];
    #pragma unroll
    for (int k = 0; k < 8; ++k) {
        int koff = (k * 32 + 8 * g) * 2;
        astrip[k] = *(const bfrag_t*)((const char*)h_lds + ((rbase + koff) ^ swz));
    }

    // TP accumulators (per path in this wave's pair)
    float accA[4];        // path 2*ph+0 (p0: a0-contract / p2: s0-contract)
    float accB[4];        // path 2*ph+1 == 1: a1-contract (scalar)
    float accB3[4][3];    // path 3: v1-contract (3 components)
    #pragma unroll
    for (int r = 0; r < 4; ++r) {
        accA[r] = 0.f; accB[r] = 0.f;
        accB3[r][0] = 0.f; accB3[r][1] = 0.f; accB3[r][2] = 0.f;
    }

    const bfrag_t* Bbase = (const bfrag_t*)w2p + lane;

    #pragma unroll
    for (int pp = 0; pp < 2; ++pp) {
        const int p = 2 * ph + pp;
        #pragma unroll
        for (int nt = 0; nt < 16; ++nt) {
            facc_t acc = (facc_t){0.f, 0.f, 0.f, 0.f};
            #pragma unroll
            for (int k = 0; k < 8; ++k) {
                bfrag_t b = Bbase[(size_t)(((p * 16 + nt) * 8 + k)) * 64];
                acc = __builtin_amdgcn_mfma_f32_16x16x32_bf16(astrip[k], b, acc, 0, 0, 0);
            }
            // TP reduce for u = nt (linear in W: per-u partials accumulate)
            #pragma unroll
            for (int r = 0; r < 4; ++r) {
                int e = 16 * mw + 4 * g + r;
                float wvl = acc[r];
                if (ph == 0) {
                    if (pp == 0) accA[r] += a0_lds[e][nt] * wvl;
                    else         accB[r] += a1_lds[e][nt] * wvl;
                } else {
                    if (pp == 0) accA[r] += x_lds[e][nt] * wvl;
                    else {
                        accB3[r][0] += x_lds[e][16 + nt * 3 + 0] * wvl;
                        accB3[r][1] += x_lds[e][16 + nt * 3 + 1] * wvl;
                        accB3[r][2] += x_lds[e][16 + nt * 3 + 2] * wvl;
                    }
                }
            }
        }
    }

    __syncthreads();   // ALL h_lds reads complete -> r* may overwrite hbuf

    #pragma unroll
    for (int r = 0; r < 4; ++r) {
        int e = 16 * mw + 4 * g + r;
        if (ph == 0) {
            r0_lds[e * 17 + v] = accA[r];
            r1_lds[e * 17 + v] = accB[r];
        } else {
            r2_lds[e * 17 + v] = accA[r];
            r3_lds[e * 49 + v * 3 + 0] = accB3[r][0];
            r3_lds[e * 49 + v * 3 + 1] = accB3[r][1];
            r3_lds[e * 49 + v * 3 + 2] = accB3[r][2];
        }
    }
    __syncthreads();   // r* ready; all x_lds/a*_lds reads done -> vbuf may alias x_lds

    // ---- phase D: combine per-edge outputs, run-merge by dst, reduced atomics ----
    {
        float scale = rsqrtf((float)nn[0]);
        const float pw0 = 0.17677669529663687f;          // sqrt(1/32); pw1/sqrt(3) == pw0
        float k0 = pw0 * scale;
        float k1 = k0 * 0.57735026918962576f;            // extra 1/sqrt(3) on path 1

        int e  = tid >> 3;
        int j0 = (tid & 7) * 8;
        float y0  = sh_lds[e][0];
        float y1x = sh_lds[e][1], y1y = sh_lds[e][2], y1z = sh_lds[e][3];
        #pragma unroll
        for (int jj = 0; jj < 8; ++jj) {
            int j = j0 + jj;
            float val;
            if (j < 16) {
                val = k0 * r0_lds[e * 17 + j] + k1 * r1_lds[e * 17 + j];
            } else {
                int t2 = j - 16;
                int vv = t2 / 3;
                int i  = t2 - vv * 3;
                float y1i = (i == 0) ? y1x : ((i == 1) ? y1y : y1z);
                val = k0 * (y1i * r2_lds[e * 17 + vv] + y0 * r3_lds[e * 49 + t2]);
            }
            vbuf[e * 68 + j] = val;
        }
    }
    if (tid < TE)
        head_lds[tid] = (tid == 0) || (dst_lds[tid] != dst_lds[tid - 1]);
    __syncthreads();
    {
        int e   = tid >> 3;
        int oct = tid & 7;
        if (head_lds[e]) {
            int L = 1;
            while (e + L < TE && !head_lds[e + L]) ++L;
            float4 s0 = *(const float4*)(vbuf + e * 68 + oct * 8);
            float4 s1 = *(const float4*)(vbuf + e * 68 + oct * 8 + 4);
            for (int i = 1; i < L; ++i) {
                const float4* q = (const float4*)(vbuf + (e + i) * 68 + oct * 8);
                float4 t0 = q[0], t1 = q[1];
                s0.x += t0.x; s0.y += t0.y; s0.z += t0.z; s0.w += t0.w;
                s1.x += t1.x; s1.y += t1.y; s1.z += t1.z; s1.w += t1.w;
            }
            float* op = outg + (size_t)dst_lds[e] * 64 + oct * 8;
            atomicAdd(op + 0, s0.x); atomicAdd(op + 1, s0.y);
            atomicAdd(op + 2, s0.z); atomicAdd(op + 3, s0.w);
            atomicAdd(op + 4, s1.x); atomicAdd(op + 5, s1.y);
            atomicAdd(op + 6, s1.z); atomicAdd(op + 7, s1.w);
        }
    }
}

extern "C" void kernel_launch(void* const* d_in, const int* in_sizes, int n_in,
                              void* d_out, int out_size, void* d_ws, size_t ws_size,
                              hipStream_t stream) {
    const int*   esrc  = (const int*)d_in[0];
    const int*   edst  = (const int*)d_in[1];
    const float* nodef = (const float*)d_in[2];
    const float* esh   = (const float*)d_in[3];
    const float* ellv  = (const float*)d_in[4];
    const float* w1    = (const float*)d_in[5];
    const float* w2    = (const float*)d_in[6];
    const int*   nn    = (const int*)d_in[7];
    float* outg = (float*)d_out;

    char* ws = (char*)d_ws;
    short* w2p    = (short*)ws;                        // 512 KiB
    int*   counts = (int*)(ws + (512 << 10));          // 40 KB
    int*   cursor = (int*)(ws + (512 << 10) + 65536);  // 40 KB
    int*   permv  = (int*)(ws + (512 << 10) + 131072); // 640 KB

    hipMemsetAsync(d_out, 0, (size_t)out_size * sizeof(float), stream);
    pack_w2<<<1024, 256, 0, stream>>>(w2, w2p);
    zero_counts<<<(N_NODES + 255) / 256, 256, 0, stream>>>(counts);
    hist_kernel<<<N_EDGES / 256, 256, 0, stream>>>(edst, counts);
    scan_kernel<<<1, 256, 0, stream>>>(counts, cursor);
    scatter_kernel<<<N_EDGES / 256, 256, 0, stream>>>(edst, cursor, permv);
    conv_kernel<<<N_EDGES / TE, 512, 0, stream>>>(permv, esrc, edst, nodef, esh, ellv,
                                                  w1, w2p, nn, outg);
}

// Round 12
// 357.476 us; speedup vs baseline: 11.0146x; 1.1547x over previous
//
#include <hip/hip_runtime.h>
#include <hip/hip_bf16.h>

#define N_NODES 10000
#define N_EDGES 160000
#define TE 64   // edges per block; 512 threads = 8 waves = 4 paths x 2 m-halves

typedef __attribute__((ext_vector_type(8))) short bfrag_t;   // 8 x bf16
typedef __attribute__((ext_vector_type(4))) float facc_t;    // 4 x f32

__device__ inline short f2bf(float f) {
    union { float f; unsigned u; } x; x.f = f;
    unsigned r = x.u + 0x7FFFu + ((x.u >> 16) & 1u);
    return (short)(r >> 16);
}

// Pack W2 (256x1024 f32, row-major) into MFMA B fragments, bf16, 1/16 folded.
// (known-good round-2/3/5 version)
__global__ void pack_w2(const float* __restrict__ w2, short* __restrict__ outp) {
    int g = blockIdx.x * blockDim.x + threadIdx.x;  // 0..262143
    int j    = g & 7;
    int lane = (g >> 3) & 63;
    int k    = (g >> 9) & 7;
    int nt   = (g >> 12) & 15;
    int p    = g >> 16;
    int row = k * 32 + ((lane >> 4) << 3) + j;
    int col = p * 256 + nt * 16 + (lane & 15);
    outp[g] = f2bf(w2[row * 1024 + col] * 0.0625f);
}

// ---- dst-sort infrastructure (unchanged, known-good) ----
__global__ void zero_counts(int* __restrict__ counts) {
    int i = blockIdx.x * blockDim.x + threadIdx.x;
    if (i < N_NODES) counts[i] = 0;
}

__global__ void hist_kernel(const int* __restrict__ edst, int* __restrict__ counts) {
    int e = blockIdx.x * blockDim.x + threadIdx.x;
    if (e < N_EDGES) atomicAdd(&counts[edst[e]], 1);
}

__global__ __launch_bounds__(256) void scan_kernel(const int* __restrict__ counts,
                                                   int* __restrict__ cursor) {
    __shared__ int part[256];
    const int t = threadIdx.x;
    const int CH = 40;
    int base = t * CH;
    int s = 0;
    for (int i = 0; i < CH; ++i) {
        int idx = base + i;
        if (idx < N_NODES) s += counts[idx];
    }
    part[t] = s;
    __syncthreads();
    for (int off = 1; off < 256; off <<= 1) {
        int add = (t >= off) ? part[t - off] : 0;
        __syncthreads();
        part[t] += add;
        __syncthreads();
    }
    int run = part[t] - s;
    for (int i = 0; i < CH; ++i) {
        int idx = base + i;
        if (idx < N_NODES) {
            cursor[idx] = run;
            run += counts[idx];
        }
    }
}

__global__ void scatter_kernel(const int* __restrict__ edst, int* __restrict__ cursor,
                               int* __restrict__ perm) {
    int e = blockIdx.x * blockDim.x + threadIdx.x;
    if (e < N_EDGES) {
        int pos = atomicAdd(&cursor[edst[e]], 1);
        perm[pos] = e;
    }
}

__global__ __launch_bounds__(512) void conv_kernel(
    const int* __restrict__ perm,
    const int* __restrict__ esrc, const int* __restrict__ edst,
    const float* __restrict__ nodef, const float* __restrict__ esh,
    const float* __restrict__ ell, const float* __restrict__ w1,
    const short* __restrict__ w2p, const int* __restrict__ nn,
    float* __restrict__ outg)
{
    // hbuf: h (bf16, 64 rows x 512B, XOR-swizzled) during phases B/C;
    // r0..r3 (f32) after the post-C barrier (25600B of 32768). [r7-verified layout]
    __shared__ __align__(16) char hbuf[TE * 512];               // 32 KB
    short* h_lds  = (short*)hbuf;
    float* r0_lds = (float*)hbuf;                               // [64][17], 4352 B
    float* r1_lds = (float*)(hbuf + 4352);                      // [64][17]
    float* r2_lds = (float*)(hbuf + 8704);                      // [64][17]
    float* r3_lds = (float*)(hbuf + 13056);                     // [64][49], ends 25600
    // x_lds during phases B/C; vbuf (64x68 f32, stride 68) during phase D
    __shared__ __align__(16) float x_lds[TE][68];               // 17408 B
    float* vbuf = (float*)x_lds;
    __shared__ float a0_lds[TE][17];   // s0*y0
    __shared__ float a1_lds[TE][17];   // sum_i v1[u][i]*y1[i]
    __shared__ float sh_lds[TE][4];
    __shared__ float el_lds[TE][3];
    __shared__ int   src_lds[TE];
    __shared__ int   dst_lds[TE];
    __shared__ int   head_lds[TE];

    const int tid = threadIdx.x;
    const int e0  = blockIdx.x * TE;

    // ---- phase A: gathered edge-wise loads (via perm) [r7-verified] ----
    if (tid < TE) {
        int pe = perm[e0 + tid];
        src_lds[tid] = esrc[pe];
        dst_lds[tid] = edst[pe];
        float4 s4 = *(const float4*)(esh + (size_t)pe * 4);
        sh_lds[tid][0] = s4.x; sh_lds[tid][1] = s4.y;
        sh_lds[tid][2] = s4.z; sh_lds[tid][3] = s4.w;
        const float* lp = ell + (size_t)pe * 3;
        el_lds[tid][0] = lp[0]; el_lds[tid][1] = lp[1]; el_lds[tid][2] = lp[2];
    }
    __syncthreads();

    // ---- phase B: x gather + h compute (r5 per-thread code, 8 thr/edge) ----
    {
        int e = tid >> 3, part = tid & 7;
        int s = src_lds[e];
        const float4* sp = (const float4*)(nodef + (size_t)s * 64 + part * 8);
        float4 u0 = sp[0], u1 = sp[1];
        float* xr = &x_lds[e][part * 8];
        *(float4*)(xr)     = u0;
        *(float4*)(xr + 4) = u1;
    }
    {
        int e = tid >> 3, c0 = (tid & 7) * 32;
        float l0 = el_lds[e][0], l1 = el_lds[e][1], l2 = el_lds[e][2];
        #pragma unroll
        for (int s = 0; s < 4; ++s) {
            bfrag_t hv;
            #pragma unroll
            for (int m = 0; m < 8; ++m) {
                int c = c0 + s * 8 + m;
                float a = l0 * w1[c] + l1 * w1[256 + c] + l2 * w1[512 + c];
                a = fmaxf(a, 0.f) * 0.8164965809277260f;  // sqrt(2/3), relu scale folded
                hv[m] = f2bf(a);
            }
            int byte = (e * 512 + (c0 + s * 8) * 2) ^ ((e & 7) << 4);
            *(bfrag_t*)((char*)h_lds + byte) = hv;
        }
    }
    __syncthreads();
    {
        #pragma unroll
        for (int q = tid; q < TE * 16; q += 512) {
            int e = q >> 4, u = q & 15;
            float y0 = sh_lds[e][0];
            a0_lds[e][u] = x_lds[e][u] * y0;
            a1_lds[e][u] = x_lds[e][16 + u * 3 + 0] * sh_lds[e][1]
                         + x_lds[e][16 + u * 3 + 1] * sh_lds[e][2]
                         + x_lds[e][16 + u * 3 + 2] * sh_lds[e][3];
        }
    }
    __syncthreads();

    // ---- phase C: r5's exact wave shape (2 mt x 4-nt chunks, 8 MFMA chains),
    //      8 waves = path (wv&3) x m-half (wv>>2). Per-block B amortized over 64 edges.
    const int lane = tid & 63;
    const int wv   = tid >> 6;        // 0..7
    const int p    = wv & 3;          // TP path
    const int mh   = wv >> 2;         // m-half: edges [32*mh, 32*mh+32)
    const int g    = lane >> 4;
    const int v    = lane & 15;
    const int eb   = 32 * mh;

    float acc0[2][4];
    float acc3[2][4][3];
    #pragma unroll
    for (int mt = 0; mt < 2; ++mt)
        #pragma unroll
        for (int r = 0; r < 4; ++r) {
            acc0[mt][r] = 0.f;
            acc3[mt][r][0] = 0.f; acc3[mt][r][1] = 0.f; acc3[mt][r][2] = 0.f;
        }

    const bfrag_t* Bp = (const bfrag_t*)w2p + (size_t)(p * 128) * 64 + lane;

    const int rb0 = (eb + v) * 512;        // mt=0 row
    const int rb1 = (eb + 16 + v) * 512;   // mt=1 row
    const int swz = (v & 7) << 4;          // row&7 == v&7 (eb,16 keep low 3 bits)

    #pragma unroll
    for (int ntc = 0; ntc < 4; ++ntc) {
        facc_t acc[2][4];
        #pragma unroll
        for (int mt = 0; mt < 2; ++mt)
            #pragma unroll
            for (int q = 0; q < 4; ++q)
                acc[mt][q] = (facc_t){0.f, 0.f, 0.f, 0.f};

        #pragma unroll
        for (int k = 0; k < 8; ++k) {
            int koff = (k * 32 + 8 * g) * 2;
            bfrag_t a0 = *(const bfrag_t*)((const char*)h_lds + ((rb0 + koff) ^ swz));
            bfrag_t a1 = *(const bfrag_t*)((const char*)h_lds + ((rb1 + koff) ^ swz));
            #pragma unroll
            for (int q = 0; q < 4; ++q) {
                bfrag_t b = Bp[(size_t)((ntc * 4 + q) * 8 + k) * 64];
                acc[0][q] = __builtin_amdgcn_mfma_f32_16x16x32_bf16(a0, b, acc[0][q], 0, 0, 0);
                acc[1][q] = __builtin_amdgcn_mfma_f32_16x16x32_bf16(a1, b, acc[1][q], 0, 0, 0);
            }
        }
        // TP reduction over u in this chunk (r5 pattern, edges offset by eb)
        #pragma unroll
        for (int mt = 0; mt < 2; ++mt)
            #pragma unroll
            for (int r = 0; r < 4; ++r) {
                int e = eb + mt * 16 + 4 * g + r;
                #pragma unroll
                for (int q = 0; q < 4; ++q) {
                    int u = ntc * 4 + q;
                    float wvl = acc[mt][q][r];
                    if (p == 0)       acc0[mt][r] += a0_lds[e][u] * wvl;
                    else if (p == 1)  acc0[mt][r] += a1_lds[e][u] * wvl;
                    else if (p == 2)  acc0[mt][r] += x_lds[e][u] * wvl;
                    else {
                        acc3[mt][r][0] += x_lds[e][16 + u * 3 + 0] * wvl;
                        acc3[mt][r][1] += x_lds[e][16 + u * 3 + 1] * wvl;
                        acc3[mt][r][2] += x_lds[e][16 + u * 3 + 2] * wvl;
                    }
                }
            }
    }

    __syncthreads();   // ALL h_lds reads complete -> r* may overwrite hbuf

    #pragma unroll
    for (int mt = 0; mt < 2; ++mt)
        #pragma unroll
        for (int r = 0; r < 4; ++r) {
            int e = eb + mt * 16 + 4 * g + r;
            if (p == 0)       r0_lds[e * 17 + v] = acc0[mt][r];
            else if (p == 1)  r1_lds[e * 17 + v] = acc0[mt][r];
            else if (p == 2)  r2_lds[e * 17 + v] = acc0[mt][r];
            else {
                r3_lds[e * 49 + v * 3 + 0] = acc3[mt][r][0];
                r3_lds[e * 49 + v * 3 + 1] = acc3[mt][r][1];
                r3_lds[e * 49 + v * 3 + 2] = acc3[mt][r][2];
            }
        }
    __syncthreads();   // r* ready; all x_lds/a*_lds reads done -> vbuf may alias x_lds

    // ---- phase D: combine per-edge outputs, run-merge by dst, reduced atomics ----
    {
        float scale = rsqrtf((float)nn[0]);
        const float pw0 = 0.17677669529663687f;          // sqrt(1/32); pw1/sqrt(3) == pw0
        float k0 = pw0 * scale;
        float k1 = k0 * 0.57735026918962576f;            // extra 1/sqrt(3) on path 1

        int e  = tid >> 3;
        int j0 = (tid & 7) * 8;
        float y0  = sh_lds[e][0];
        float y1x = sh_lds[e][1], y1y = sh_lds[e][2], y1z = sh_lds[e][3];
        #pragma unroll
        for (int jj = 0; jj < 8; ++jj) {
            int j = j0 + jj;
            float val;
            if (j < 16) {
                val = k0 * r0_lds[e * 17 + j] + k1 * r1_lds[e * 17 + j];
            } else {
                int t2 = j - 16;
                int vv = t2 / 3;
                int i  = t2 - vv * 3;
                float y1i = (i == 0) ? y1x : ((i == 1) ? y1y : y1z);
                val = k0 * (y1i * r2_lds[e * 17 + vv] + y0 * r3_lds[e * 49 + t2]);
            }
            vbuf[e * 68 + j] = val;
        }
    }
    if (tid < TE)
        head_lds[tid] = (tid == 0) || (dst_lds[tid] != dst_lds[tid - 1]);
    __syncthreads();
    {
        int e   = tid >> 3;
        int oct = tid & 7;
        if (head_lds[e]) {
            int L = 1;
            while (e + L < TE && !head_lds[e + L]) ++L;
            float4 s0 = *(const float4*)(vbuf + e * 68 + oct * 8);
            float4 s1 = *(const float4*)(vbuf + e * 68 + oct * 8 + 4);
            for (int i = 1; i < L; ++i) {
                const float4* q = (const float4*)(vbuf + (e + i) * 68 + oct * 8);
                float4 t0 = q[0], t1 = q[1];
                s0.x += t0.x; s0.y += t0.y; s0.z += t0.z; s0.w += t0.w;
                s1.x += t1.x; s1.y += t1.y; s1.z += t1.z; s1.w += t1.w;
            }
            float* op = outg + (size_t)dst_lds[e] * 64 + oct * 8;
            atomicAdd(op + 0, s0.x); atomicAdd(op + 1, s0.y);
            atomicAdd(op + 2, s0.z); atomicAdd(op + 3, s0.w);
            atomicAdd(op + 4, s1.x); atomicAdd(op + 5, s1.y);
            atomicAdd(op + 6, s1.z); atomicAdd(op + 7, s1.w);
        }
    }
}

extern "C" void kernel_launch(void* const* d_in, const int* in_sizes, int n_in,
                              void* d_out, int out_size, void* d_ws, size_t ws_size,
                              hipStream_t stream) {
    const int*   esrc  = (const int*)d_in[0];
    const int*   edst  = (const int*)d_in[1];
    const float* nodef = (const float*)d_in[2];
    const float* esh   = (const float*)d_in[3];
    const float* ellv  = (const float*)d_in[4];
    const float* w1    = (const float*)d_in[5];
    const float* w2    = (const float*)d_in[6];
    const int*   nn    = (const int*)d_in[7];
    float* outg = (float*)d_out;

    char* ws = (char*)d_ws;
    short* w2p    = (short*)ws;                        // 512 KiB
    int*   counts = (int*)(ws + (512 << 10));          // 40 KB
    int*   cursor = (int*)(ws + (512 << 10) + 65536);  // 40 KB
    int*   permv  = (int*)(ws + (512 << 10) + 131072); // 640 KB

    hipMemsetAsync(d_out, 0, (size_t)out_size * sizeof(float), stream);
    pack_w2<<<1024, 256, 0, stream>>>(w2, w2p);
    zero_counts<<<(N_NODES + 255) / 256, 256, 0, stream>>>(counts);
    hist_kernel<<<N_EDGES / 256, 256, 0, stream>>>(edst, counts);
    scan_kernel<<<1, 256, 0, stream>>>(counts, cursor);
    scatter_kernel<<<N_EDGES / 256, 256, 0, stream>>>(edst, cursor, permv);
    conv_kernel<<<N_EDGES / TE, 512, 0, stream>>>(permv, esrc, edst, nodef, esh, ellv,
                                                  w1, w2p, nn, outg);
}